// Round 5
// baseline (115.363 us; speedup 1.0000x reference)
//
#include <hip/hip_runtime.h>
#include <stdint.h>

// Problem constants
#define B_  16
#define C_  256
#define T_  2048
#define K_  1024
#define TOTAL_ELEMS 8388608   // B*C*T

typedef short bf16x8 __attribute__((ext_vector_type(8)));
typedef float f32x4 __attribute__((ext_vector_type(4)));

// ---------- packed (dist, idx) ordering helpers ----------
__device__ __forceinline__ unsigned long long pack_key(float d, int idx) {
  unsigned u = __float_as_uint(d);
  u = (u & 0x80000000u) ? ~u : (u | 0x80000000u);   // monotone map f32 -> u32
  return ((unsigned long long)u << 32) | (unsigned)idx;
}
__device__ __forceinline__ float unpack_dist(unsigned long long key) {
  unsigned du = (unsigned)(key >> 32);
  unsigned bits = (du & 0x80000000u) ? (du ^ 0x80000000u) : ~du;
  return __uint_as_float(bits);
}

__device__ __forceinline__ unsigned short f2bf_rne(float f) {
  unsigned u = __float_as_uint(f);
  unsigned r = u + 0x7FFFu + ((u >> 16) & 1u);
  return (unsigned short)(r >> 16);
}

__device__ __forceinline__ void gload_lds16(const void* g, void* l) {
  __builtin_amdgcn_global_load_lds(
      (const __attribute__((address_space(1))) unsigned int*)g,
      (__attribute__((address_space(3))) unsigned int*)l, 16, 0, 0);
}

// ---------- prep: norms (bid 0..11) + e0->bf16 (bid 12..267) + ws init (bid 268..335) ----------
__global__ __launch_bounds__(256) void prep_kernel(
    const float* __restrict__ e0, const float* __restrict__ e1,
    const float* __restrict__ e2, float* __restrict__ nrm,
    unsigned short* __restrict__ ebf, uint4* __restrict__ keys_region,
    float* __restrict__ loss_accum) {
  int bid = blockIdx.x;
  int tid = threadIdx.x;
  if (bid < 12) {
    int i = bid * 256 + tid;             // 0..3071
    const float* e = (i < 1024) ? e0 : (i < 2048) ? e1 : e2;
    const float* p = e + (size_t)(i & 1023) * C_;
    float s = 0.0f;
    for (int c = 0; c < C_; c += 4) {
      float4 v = *(const float4*)(p + c);
      s = fmaf(v.x, v.x, s); s = fmaf(v.y, v.y, s);
      s = fmaf(v.z, v.z, s); s = fmaf(v.w, v.w, s);
    }
    nrm[i] = s;
  } else if (bid < 268) {
    int i = (bid - 12) * 256 + tid;      // quad id, 0..65535
    float4 v = *(const float4*)(e0 + (size_t)i * 4);
    unsigned lo = (unsigned)f2bf_rne(v.x) | ((unsigned)f2bf_rne(v.y) << 16);
    unsigned hi = (unsigned)f2bf_rne(v.z) | ((unsigned)f2bf_rne(v.w) << 16);
    *(uint2*)(ebf + (size_t)i * 4) = make_uint2(lo, hi);
  } else {
    // init keys (262144 B) + keysM (16384 B) = 17408 uint4, and loss_accum
    int i = (bid - 268) * 256 + tid;     // 0..17407
    keys_region[i] = make_uint4(0xFFFFFFFFu, 0xFFFFFFFFu, 0xFFFFFFFFu, 0xFFFFFFFFu);
    if (bid == 268 && tid == 0) *loss_accum = 0.0f;
  }
}

// ---------- transpose+convert x[b][c][t] f32 -> xT[b*T+t][c] bf16, + sum(x^2) ----------
// grid = 16 * 32 * 4 = 2048 blocks, 64t x 64c tile each
__global__ __launch_bounds__(256) void xpose_kernel(
    const float* __restrict__ x, unsigned short* __restrict__ xT,
    float* __restrict__ loss_accum) {
  __shared__ float ftile[64][68];
  __shared__ float red[4];
  int tid = threadIdx.x;
  int bid = blockIdx.x;
  int b  = bid >> 7;
  int t0 = ((bid >> 2) & 31) << 6;
  int c0 = (bid & 3) << 6;
  int cr = tid >> 4;                 // 0..15
  int t_loc = (tid & 15) * 4;
  const float* src = x + (size_t)b * (C_ * T_) + (size_t)c0 * T_ + t0;
  float sq = 0.0f;
#pragma unroll
  for (int q = 0; q < 4; q++) {
    int c_loc = cr + q * 16;         // covers all 64 c rows
    float4 v = *(const float4*)(src + (size_t)c_loc * T_ + t_loc);
    *(float4*)&ftile[c_loc][t_loc] = v;
    sq = fmaf(v.x, v.x, sq); sq = fmaf(v.y, v.y, sq);
    sq = fmaf(v.z, v.z, sq); sq = fmaf(v.w, v.w, sq);
  }
  for (int off = 32; off > 0; off >>= 1) sq += __shfl_down(sq, off, 64);
  if ((tid & 63) == 0) red[tid >> 6] = sq;
  __syncthreads();
  if (tid == 0)
    atomicAdd(loss_accum, red[0] + red[1] + red[2] + red[3]);

  int t_row = tid >> 2;
  int cs = (tid & 3) * 16;
  unsigned pk[8];
#pragma unroll
  for (int i = 0; i < 8; i++) {
    unsigned short lo = f2bf_rne(ftile[cs + 2 * i][t_row]);
    unsigned short hi = f2bf_rne(ftile[cs + 2 * i + 1][t_row]);
    pk[i] = (unsigned)lo | ((unsigned)hi << 16);
  }
  unsigned short* dst = xT + ((size_t)(b * T_ + t0 + t_row) * C_ + c0 + cs);
  *(uint4*)dst       = make_uint4(pk[0], pk[1], pk[2], pk[3]);
  *((uint4*)dst + 1) = make_uint4(pk[4], pk[5], pk[6], pk[7]);
}

// ---------- code-to-code maps as tiled f32 GEMM + argmin ----------
__global__ __launch_bounds__(256) void map_tile_kernel(
    const float* __restrict__ e0, const float* __restrict__ e1,
    const float* __restrict__ e2, const float* __restrict__ nrm,
    unsigned long long* __restrict__ keysM) {
  __shared__ float As[16][68];
  __shared__ float Bs[16][68];
  int bid = blockIdx.x;
  int m = bid >> 8;
  int tb = bid & 255;
  int ar0 = (tb >> 4) << 6;
  int br0 = (tb & 15) << 6;
  const float* Ap = m ? e1 : e0;
  const float* Bp = m ? e2 : e1;
  const float* nB = nrm + (m + 1) * 1024;

  int tid = threadIdx.x;
  int ty = tid >> 4, tx = tid & 15;
  int srow = tid >> 2;
  int skp  = (tid & 3) << 2;

  float acc[4][4];
#pragma unroll
  for (int i = 0; i < 4; i++)
#pragma unroll
    for (int j = 0; j < 4; j++) acc[i][j] = 0.0f;

  const float* gA = Ap + (size_t)(ar0 + srow) * C_ + skp;
  const float* gB = Bp + (size_t)(br0 + srow) * C_ + skp;

  for (int kk = 0; kk < C_; kk += 16) {
    float4 av = *(const float4*)(gA + kk);
    float4 bv = *(const float4*)(gB + kk);
    __syncthreads();
    As[skp + 0][srow] = av.x; As[skp + 1][srow] = av.y;
    As[skp + 2][srow] = av.z; As[skp + 3][srow] = av.w;
    Bs[skp + 0][srow] = bv.x; Bs[skp + 1][srow] = bv.y;
    Bs[skp + 2][srow] = bv.z; Bs[skp + 3][srow] = bv.w;
    __syncthreads();
#pragma unroll
    for (int k = 0; k < 16; k++) {
      float4 a4 = *(const float4*)&As[k][ty * 4];
      float4 b4 = *(const float4*)&Bs[k][tx * 4];
      float aa[4] = {a4.x, a4.y, a4.z, a4.w};
      float bb[4] = {b4.x, b4.y, b4.z, b4.w};
#pragma unroll
      for (int i = 0; i < 4; i++)
#pragma unroll
        for (int j = 0; j < 4; j++)
          acc[i][j] = fmaf(aa[i], bb[j], acc[i][j]);
    }
  }

  float nv[4];
#pragma unroll
  for (int j = 0; j < 4; j++) nv[j] = nB[br0 + tx * 4 + j];

#pragma unroll
  for (int i = 0; i < 4; i++) {
    unsigned long long best = 0xFFFFFFFFFFFFFFFFULL;
#pragma unroll
    for (int j = 0; j < 4; j++) {
      int code = br0 + tx * 4 + j;
      float s = nv[j] - 2.0f * acc[i][j];
      unsigned long long key = pack_key(s, code);
      if (key < best) best = key;
    }
#pragma unroll
    for (int off = 1; off < 16; off <<= 1) {
      unsigned long long o = __shfl_xor(best, off, 64);
      if (o < best) best = o;
    }
    if (tx == 0)
      atomicMin(&keysM[m * 1024 + ar0 + ty * 4 + i], best);
  }
}

// ---------- layer-0 MFMA distance GEMM + argmin ----------
// 128x128 tile, BK=32, 4 waves (2x2). XOR k-slot swizzle keyed on (row>>1)&3:
// row stride = 64 B = 16 banks, so bank base alternates with row&1 only;
// XOR with (row>>1)&3 balances the 4 slots within each parity group -> 2-way max.
__global__ __launch_bounds__(256) void l0_mfma_kernel(
    const unsigned short* __restrict__ xT, const unsigned short* __restrict__ ebf,
    const float* __restrict__ e0n, unsigned long long* __restrict__ keys) {
  __shared__ __align__(16) unsigned short AB[2][2][128][32];
  __shared__ unsigned long long kred[128][2];

  int tid = threadIdx.x;
  int l = tid & 63, w = tid >> 6;
  int wr = w >> 1, wc = w & 1;
  int mb = blockIdx.x & 255, nb = blockIdx.x >> 8;
  int row0 = mb << 7, kb = nb << 7;

  int sm = w * 32 + (l >> 2);
  int ks = (l & 3) ^ ((l >> 3) & 3);   // source k-seg for dest slot (l&3), row=(l>>2)
  const unsigned short* gA = xT + ((size_t)(row0 + sm) * C_ + ks * 8);
  const unsigned short* gB = ebf + ((size_t)(kb + sm) * C_ + ks * 8);

  f32x4 acc[4][4];
#pragma unroll
  for (int mi = 0; mi < 4; mi++)
#pragma unroll
    for (int ni = 0; ni < 4; ni++) acc[mi][ni] = (f32x4){0.f, 0.f, 0.f, 0.f};

#define STAGE(buf, kk) do {                                              \
    char* baseA = (char*)&AB[(buf)][0][0][0] + w * 2048;                 \
    char* baseB = (char*)&AB[(buf)][1][0][0] + w * 2048;                 \
    gload_lds16(gA + (size_t)(kk) * 32, baseA);                          \
    gload_lds16(gA + (size_t)16 * C_ + (size_t)(kk) * 32, baseA + 1024); \
    gload_lds16(gB + (size_t)(kk) * 32, baseB);                          \
    gload_lds16(gB + (size_t)16 * C_ + (size_t)(kk) * 32, baseB + 1024); \
  } while (0)

  STAGE(0, 0);
  __syncthreads();

  int lr = l & 15, lg = l >> 4;
  int slot = lg ^ ((lr >> 1) & 3);     // read-side: same involution
  int buf = 0;
  for (int kk = 0; kk < 8; kk++) {
    if (kk < 7) STAGE(buf ^ 1, kk + 1);
    bf16x8 aF[4], bF[4];
#pragma unroll
    for (int mi = 0; mi < 4; mi++)
      aF[mi] = *(const bf16x8*)&AB[buf][0][wr * 64 + mi * 16 + lr][slot * 8];
#pragma unroll
    for (int ni = 0; ni < 4; ni++)
      bF[ni] = *(const bf16x8*)&AB[buf][1][wc * 64 + ni * 16 + lr][slot * 8];
#pragma unroll
    for (int mi = 0; mi < 4; mi++)
#pragma unroll
      for (int ni = 0; ni < 4; ni++)
        acc[mi][ni] = __builtin_amdgcn_mfma_f32_16x16x32_bf16(
            aF[mi], bF[ni], acc[mi][ni], 0, 0, 0);
    __syncthreads();
    buf ^= 1;
  }
#undef STAGE

  float nv[4];
#pragma unroll
  for (int ni = 0; ni < 4; ni++) nv[ni] = e0n[kb + wc * 64 + ni * 16 + lr];

#pragma unroll
  for (int mi = 0; mi < 4; mi++) {
#pragma unroll
    for (int r = 0; r < 4; r++) {
      unsigned long long best = 0xFFFFFFFFFFFFFFFFULL;
#pragma unroll
      for (int ni = 0; ni < 4; ni++) {
        int code = kb + wc * 64 + ni * 16 + lr;
        float s = nv[ni] - 2.0f * acc[mi][ni][r];
        unsigned long long key = pack_key(s, code);
        if (key < best) best = key;
      }
#pragma unroll
      for (int off = 1; off < 16; off <<= 1) {
        unsigned long long o = __shfl_xor(best, off, 64);
        if (o < best) best = o;
      }
      if (lr == 0) kred[wr * 64 + mi * 16 + lg * 4 + r][wc] = best;
    }
  }
  __syncthreads();
  if (tid < 128) {
    unsigned long long b0 = kred[tid][0], b1 = kred[tid][1];
    atomicMin(&keys[row0 + tid], b0 < b1 ? b0 : b1);
  }
}

// ---------- gather output + per-(b,t) loss terms (x no longer read) ----------
__global__ __launch_bounds__(256) void finish_kernel(
    const float* __restrict__ emb2,
    const unsigned long long* __restrict__ keys,
    const unsigned long long* __restrict__ keysM,
    const float* __restrict__ nrm,
    float* __restrict__ out, float* __restrict__ loss_accum) {
  __shared__ int code2_l[64];
  __shared__ float rloss[64];
  int tid = threadIdx.x;
  int b  = blockIdx.x >> 5;
  int t0 = (blockIdx.x & 31) << 6;
  int tt = tid & 63, w = tid >> 6;

  if (w == 0) {
    unsigned long long key0 = keys[(size_t)b * T_ + t0 + tt];
    int idx0 = (int)(key0 & 0xFFFFFFFFULL);
    float s0 = unpack_dist(key0);
    unsigned long long k1 = keysM[idx0];
    int c1 = (int)(k1 & 0xFFFFFFFFULL);
    unsigned long long k2 = keysM[1024 + c1];
    code2_l[tt] = (int)(k2 & 0xFFFFFFFFULL);
    rloss[tt] = s0 + nrm[idx0] + unpack_dist(k1) + nrm[1024 + c1] + unpack_dist(k2);
  }
  __syncthreads();

  float* ob = out + ((size_t)b << 19);
  int code2 = code2_l[tt];
  const float* e2row = emb2 + (size_t)code2 * C_;
  for (int c4 = w * 64; c4 < w * 64 + 64; c4 += 4) {
    float4 ev = *(const float4*)(e2row + c4);
    float evv[4] = {ev.x, ev.y, ev.z, ev.w};
#pragma unroll
    for (int u = 0; u < 4; u++)
      ob[(size_t)(c4 + u) * T_ + t0 + tt] = evv[u];
  }
  if (w == 0) {
    float tot = rloss[tt];
    for (int off = 32; off > 0; off >>= 1)
      tot += __shfl_down(tot, off, 64);
    if (tt == 0) atomicAdd(loss_accum, tot);
  }
}

__global__ void finalize_kernel(const float* __restrict__ loss_accum,
                                float* __restrict__ out_loss) {
  *out_loss = 2.0f * (*loss_accum) / 8388608.0f;
}

extern "C" void kernel_launch(void* const* d_in, const int* in_sizes, int n_in,
                              void* d_out, int out_size, void* d_ws, size_t ws_size,
                              hipStream_t stream) {
  const float* x  = (const float*)d_in[0];
  const float* e0 = (const float*)d_in[1];
  const float* e1 = (const float*)d_in[2];
  const float* e2 = (const float*)d_in[3];
  float* out = (float*)d_out;
  char* ws = (char*)d_ws;

  unsigned long long* keys  = (unsigned long long*)ws;            // 262144 B
  unsigned long long* keysM = (unsigned long long*)(ws + 262144); // 16384 B
  float* nrm  = (float*)(ws + 278528);                            // 12288 B
  float* loss_accum = (float*)(ws + 290816);                      // 4 B
  unsigned short* embbf = (unsigned short*)(ws + 294912);         // 524288 B
  unsigned short* xT    = (unsigned short*)(ws + 819200);         // 16777216 B

  prep_kernel<<<336, 256, 0, stream>>>(e0, e1, e2, nrm, embbf, (uint4*)ws, loss_accum);
  xpose_kernel<<<2048, 256, 0, stream>>>(x, xT, loss_accum);
  l0_mfma_kernel<<<2048, 256, 0, stream>>>(xT, embbf, nrm, keys);
  map_tile_kernel<<<512, 256, 0, stream>>>(e0, e1, e2, nrm, keysM);
  finish_kernel<<<512, 256, 0, stream>>>(e2, keys, keysM, nrm, out, loss_accum);
  finalize_kernel<<<1, 1, 0, stream>>>(loss_accum, out + TOTAL_ELEMS);
}

// Round 6
// 110.690 us; speedup vs baseline: 1.0422x; 1.0422x over previous
//
#include <hip/hip_runtime.h>
#include <stdint.h>

// Problem constants
#define B_  16
#define C_  256
#define T_  2048
#define K_  1024
#define TOTAL_ELEMS 8388608   // B*C*T

typedef short bf16x8 __attribute__((ext_vector_type(8)));
typedef float f32x4 __attribute__((ext_vector_type(4)));

// ---------- packed (dist, idx) ordering helpers ----------
__device__ __forceinline__ unsigned long long pack_key(float d, int idx) {
  unsigned u = __float_as_uint(d);
  u = (u & 0x80000000u) ? ~u : (u | 0x80000000u);   // monotone map f32 -> u32
  return ((unsigned long long)u << 32) | (unsigned)idx;
}
__device__ __forceinline__ float unpack_dist(unsigned long long key) {
  unsigned du = (unsigned)(key >> 32);
  unsigned bits = (du & 0x80000000u) ? (du ^ 0x80000000u) : ~du;
  return __uint_as_float(bits);
}

__device__ __forceinline__ unsigned short f2bf_rne(float f) {
  unsigned u = __float_as_uint(f);
  unsigned r = u + 0x7FFFu + ((u >> 16) & 1u);
  return (unsigned short)(r >> 16);
}

__device__ __forceinline__ void gload_lds16(const void* g, void* l) {
  __builtin_amdgcn_global_load_lds(
      (const __attribute__((address_space(1))) unsigned int*)g,
      (__attribute__((address_space(3))) unsigned int*)l, 16, 0, 0);
}

// ---------- prep: norms (0..11) + e0->bf16 (12..267) + keysM/loss init (268..271) ----------
__global__ __launch_bounds__(256) void prep_kernel(
    const float* __restrict__ e0, const float* __restrict__ e1,
    const float* __restrict__ e2, float* __restrict__ nrm,
    unsigned short* __restrict__ ebf, uint4* __restrict__ keysM_region,
    float* __restrict__ loss_accum) {
  int bid = blockIdx.x;
  int tid = threadIdx.x;
  if (bid < 12) {
    int i = bid * 256 + tid;             // 0..3071
    const float* e = (i < 1024) ? e0 : (i < 2048) ? e1 : e2;
    const float* p = e + (size_t)(i & 1023) * C_;
    float s = 0.0f;
    for (int c = 0; c < C_; c += 4) {
      float4 v = *(const float4*)(p + c);
      s = fmaf(v.x, v.x, s); s = fmaf(v.y, v.y, s);
      s = fmaf(v.z, v.z, s); s = fmaf(v.w, v.w, s);
    }
    nrm[i] = s;
  } else if (bid < 268) {
    int i = (bid - 12) * 256 + tid;      // quad id, 0..65535
    float4 v = *(const float4*)(e0 + (size_t)i * 4);
    unsigned lo = (unsigned)f2bf_rne(v.x) | ((unsigned)f2bf_rne(v.y) << 16);
    unsigned hi = (unsigned)f2bf_rne(v.z) | ((unsigned)f2bf_rne(v.w) << 16);
    *(uint2*)(ebf + (size_t)i * 4) = make_uint2(lo, hi);
  } else {
    // init keysM (16384 B = 1024 uint4) + loss_accum
    int i = (bid - 268) * 256 + tid;     // 0..1023
    keysM_region[i] = make_uint4(0xFFFFFFFFu, 0xFFFFFFFFu, 0xFFFFFFFFu, 0xFFFFFFFFu);
    if (bid == 268 && tid == 0) *loss_accum = 0.0f;
  }
}

// ---------- transpose+convert x[b][c][t] f32 -> xT[b*T+t][c] bf16, + sum(x^2) ----------
__global__ __launch_bounds__(256) void xpose_kernel(
    const float* __restrict__ x, unsigned short* __restrict__ xT,
    float* __restrict__ loss_accum) {
  __shared__ float ftile[64][68];
  __shared__ float red[4];
  int tid = threadIdx.x;
  int bid = blockIdx.x;
  int b  = bid >> 7;
  int t0 = ((bid >> 2) & 31) << 6;
  int c0 = (bid & 3) << 6;
  int cr = tid >> 4;                 // 0..15
  int t_loc = (tid & 15) * 4;
  const float* src = x + (size_t)b * (C_ * T_) + (size_t)c0 * T_ + t0;
  float sq = 0.0f;
#pragma unroll
  for (int q = 0; q < 4; q++) {
    int c_loc = cr + q * 16;
    float4 v = *(const float4*)(src + (size_t)c_loc * T_ + t_loc);
    *(float4*)&ftile[c_loc][t_loc] = v;
    sq = fmaf(v.x, v.x, sq); sq = fmaf(v.y, v.y, sq);
    sq = fmaf(v.z, v.z, sq); sq = fmaf(v.w, v.w, sq);
  }
  for (int off = 32; off > 0; off >>= 1) sq += __shfl_down(sq, off, 64);
  if ((tid & 63) == 0) red[tid >> 6] = sq;
  __syncthreads();
  if (tid == 0)
    atomicAdd(loss_accum, red[0] + red[1] + red[2] + red[3]);

  int t_row = tid >> 2;
  int cs = (tid & 3) * 16;
  unsigned pk[8];
#pragma unroll
  for (int i = 0; i < 8; i++) {
    unsigned short lo = f2bf_rne(ftile[cs + 2 * i][t_row]);
    unsigned short hi = f2bf_rne(ftile[cs + 2 * i + 1][t_row]);
    pk[i] = (unsigned)lo | ((unsigned)hi << 16);
  }
  unsigned short* dst = xT + ((size_t)(b * T_ + t0 + t_row) * C_ + c0 + cs);
  *(uint4*)dst       = make_uint4(pk[0], pk[1], pk[2], pk[3]);
  *((uint4*)dst + 1) = make_uint4(pk[4], pk[5], pk[6], pk[7]);
}

// ---------- code-to-code maps as tiled f32 GEMM + argmin ----------
__global__ __launch_bounds__(256) void map_tile_kernel(
    const float* __restrict__ e0, const float* __restrict__ e1,
    const float* __restrict__ e2, const float* __restrict__ nrm,
    unsigned long long* __restrict__ keysM) {
  __shared__ float As[16][68];
  __shared__ float Bs[16][68];
  int bid = blockIdx.x;
  int m = bid >> 8;
  int tb = bid & 255;
  int ar0 = (tb >> 4) << 6;
  int br0 = (tb & 15) << 6;
  const float* Ap = m ? e1 : e0;
  const float* Bp = m ? e2 : e1;
  const float* nB = nrm + (m + 1) * 1024;

  int tid = threadIdx.x;
  int ty = tid >> 4, tx = tid & 15;
  int srow = tid >> 2;
  int skp  = (tid & 3) << 2;

  float acc[4][4];
#pragma unroll
  for (int i = 0; i < 4; i++)
#pragma unroll
    for (int j = 0; j < 4; j++) acc[i][j] = 0.0f;

  const float* gA = Ap + (size_t)(ar0 + srow) * C_ + skp;
  const float* gB = Bp + (size_t)(br0 + srow) * C_ + skp;

  for (int kk = 0; kk < C_; kk += 16) {
    float4 av = *(const float4*)(gA + kk);
    float4 bv = *(const float4*)(gB + kk);
    __syncthreads();
    As[skp + 0][srow] = av.x; As[skp + 1][srow] = av.y;
    As[skp + 2][srow] = av.z; As[skp + 3][srow] = av.w;
    Bs[skp + 0][srow] = bv.x; Bs[skp + 1][srow] = bv.y;
    Bs[skp + 2][srow] = bv.z; Bs[skp + 3][srow] = bv.w;
    __syncthreads();
#pragma unroll
    for (int k = 0; k < 16; k++) {
      float4 a4 = *(const float4*)&As[k][ty * 4];
      float4 b4 = *(const float4*)&Bs[k][tx * 4];
      float aa[4] = {a4.x, a4.y, a4.z, a4.w};
      float bb[4] = {b4.x, b4.y, b4.z, b4.w};
#pragma unroll
      for (int i = 0; i < 4; i++)
#pragma unroll
        for (int j = 0; j < 4; j++)
          acc[i][j] = fmaf(aa[i], bb[j], acc[i][j]);
    }
  }

  float nv[4];
#pragma unroll
  for (int j = 0; j < 4; j++) nv[j] = nB[br0 + tx * 4 + j];

#pragma unroll
  for (int i = 0; i < 4; i++) {
    unsigned long long best = 0xFFFFFFFFFFFFFFFFULL;
#pragma unroll
    for (int j = 0; j < 4; j++) {
      int code = br0 + tx * 4 + j;
      float s = nv[j] - 2.0f * acc[i][j];
      unsigned long long key = pack_key(s, code);
      if (key < best) best = key;
    }
#pragma unroll
    for (int off = 1; off < 16; off <<= 1) {
      unsigned long long o = __shfl_xor(best, off, 64);
      if (o < best) best = o;
    }
    if (tx == 0)
      atomicMin(&keysM[m * 1024 + ar0 + ty * 4 + i], best);
  }
}

// ---------- layer-0 MFMA distance GEMM + argmin (A-resident, code-streaming) ----------
// 256 blocks (1/CU), 128 rows each. A[128][256] bf16 resident in LDS (64 KB),
// swizzled: elem(row,kk,seg) @ byte row*512 + (kk^((row>>2)&1))*64 + (seg^(row&3))*16
// -> all frag reads hit the 8-cycle LDS BW floor. Codes stream as 4 pairs of
// 2x128-chunks; B-slice (256 codes x 32 k, seg^=code&3) double-buffered (2x16 KB).
// Running argmin in registers: acc init = -||e||^2/2 so acc_final = -s/2;
// track (max acc, meta) per (mi,r); keys written directly (no atomics/init).
__global__ __launch_bounds__(256, 1) void l0_mfma_kernel(
    const unsigned short* __restrict__ xT, const unsigned short* __restrict__ ebf,
    const float* __restrict__ e0n, unsigned long long* __restrict__ keys) {
  extern __shared__ char smem[];            // 96 KB dynamic
  char* Abuf = smem;                        // 64 KB
  char* Bbuf = smem + 65536;                // 32 KB (2 x 16 KB dbuf)

  int tid = threadIdx.x;
  int l = tid & 63, w = tid >> 6;
  int wr = w >> 1, wc = w & 1;
  int row0 = blockIdx.x << 7;
  int lr = l & 15, lg = l >> 4;

  // ---- stage A: wave w stages rows [w*32, w*32+32), 16 wave-gloads of 1 KB ----
  {
    char* abase = Abuf + w * 16384;
    int q = (l & 31) >> 2;
    int s = l & 3;
    int rsub = l >> 5;
#pragma unroll
    for (int i = 0; i < 16; i++) {
      int row = w * 32 + i * 2 + rsub;
      int kelem = (((q ^ ((row >> 2) & 1)) << 5) + ((s ^ (row & 3)) << 3));
      gload_lds16(xT + (((size_t)(row0 + row)) << 8) + kelem, abase + i * 1024);
    }
  }

  // ---- B staging: pair p, k-step kk -> dbuf d; wave w covers codes [w*64, w*64+64) ----
#define STAGEB(d, p, kk) do {                                            \
    char* bbase = Bbuf + (d) * 16384 + w * 4096;                         \
    _Pragma("unroll")                                                    \
    for (int i_ = 0; i_ < 4; i_++) {                                     \
      int code_ = (p) * 256 + w * 64 + i_ * 16 + (l >> 2);               \
      int kelem_ = ((kk) << 5) + (((l & 3) ^ (code_ & 3)) << 3);         \
      gload_lds16(ebf + (((size_t)code_) << 8) + kelem_, bbase + i_ * 1024); \
    } } while (0)

  f32x4 acc[2][4][4];
  float bestv[4][4];
  int   bestm[4][4];
#pragma unroll
  for (int mi = 0; mi < 4; mi++)
#pragma unroll
    for (int r = 0; r < 4; r++) { bestv[mi][r] = -1e30f; bestm[mi][r] = 0; }

  STAGEB(0, 0, 0);
  __syncthreads();

  int aseg = (lg ^ (lr & 3)) << 4;     // swizzled 16B-seg (same for A and B reads)
  int akb1 = (lr >> 2) & 1;            // A kk-bit swizzle
  int d = 0;
  for (int p = 0; p < 4; p++) {
    // init acc with -||e||^2 / 2
#pragma unroll
    for (int c01 = 0; c01 < 2; c01++)
#pragma unroll
      for (int ni = 0; ni < 4; ni++) {
        float iv = -0.5f * e0n[p * 256 + c01 * 128 + wc * 64 + ni * 16 + lr];
        f32x4 ivv = {iv, iv, iv, iv};
#pragma unroll
        for (int mi = 0; mi < 4; mi++) acc[c01][mi][ni] = ivv;
      }
#pragma unroll
    for (int kk = 0; kk < 8; kk++) {
      if (kk < 7) { STAGEB(d ^ 1, p, kk + 1); }
      else if (p < 3) { STAGEB(d ^ 1, p + 1, 0); }
      bf16x8 aF[4], bF[2][4];
#pragma unroll
      for (int mi = 0; mi < 4; mi++)
        aF[mi] = *(const bf16x8*)(Abuf + (wr * 64 + mi * 16 + lr) * 512 +
                                  ((kk ^ akb1) << 6) + aseg);
#pragma unroll
      for (int c01 = 0; c01 < 2; c01++)
#pragma unroll
        for (int ni = 0; ni < 4; ni++)
          bF[c01][ni] = *(const bf16x8*)(Bbuf + d * 16384 +
                        (c01 * 128 + wc * 64 + ni * 16 + lr) * 64 + aseg);
#pragma unroll
      for (int c01 = 0; c01 < 2; c01++)
#pragma unroll
        for (int mi = 0; mi < 4; mi++)
#pragma unroll
          for (int ni = 0; ni < 4; ni++)
            acc[c01][mi][ni] = __builtin_amdgcn_mfma_f32_16x16x32_bf16(
                aF[mi], bF[c01][ni], acc[c01][mi][ni], 0, 0, 0);
      __syncthreads();
      d ^= 1;
    }
    // fold this pair into running best (strict > keeps lowest code on ties)
    int pm = p * 8;
#pragma unroll
    for (int mi = 0; mi < 4; mi++)
#pragma unroll
      for (int r = 0; r < 4; r++)
#pragma unroll
        for (int c01 = 0; c01 < 2; c01++)
#pragma unroll
          for (int ni = 0; ni < 4; ni++) {
            float v = acc[c01][mi][ni][r];
            if (v > bestv[mi][r]) { bestv[mi][r] = v; bestm[mi][r] = pm + c01 * 4 + ni; }
          }
  }
#undef STAGEB

  // ---- epilogue: cross-lane reduce, direct keys write (Bbuf reused as kred) ----
  unsigned long long (*kred)[2] = (unsigned long long(*)[2])Bbuf;
#pragma unroll
  for (int mi = 0; mi < 4; mi++)
#pragma unroll
    for (int r = 0; r < 4; r++) {
      float sdist = -2.0f * bestv[mi][r];
      int m = bestm[mi][r];
      int code = ((m >> 3) << 8) | (((m >> 2) & 1) << 7) | (wc << 6) |
                 ((m & 3) << 4) | lr;
      unsigned long long key = pack_key(sdist, code);
#pragma unroll
      for (int off = 1; off < 16; off <<= 1) {
        unsigned long long o = __shfl_xor(key, off, 64);
        if (o < key) key = o;
      }
      if (lr == 0) kred[wr * 64 + mi * 16 + lg * 4 + r][wc] = key;
    }
  __syncthreads();
  if (tid < 128) {
    unsigned long long a = kred[tid][0], b = kred[tid][1];
    keys[row0 + tid] = a < b ? a : b;
  }
}

// ---------- gather output + per-(b,t) loss terms ----------
__global__ __launch_bounds__(256) void finish_kernel(
    const float* __restrict__ emb2,
    const unsigned long long* __restrict__ keys,
    const unsigned long long* __restrict__ keysM,
    const float* __restrict__ nrm,
    float* __restrict__ out, float* __restrict__ loss_accum) {
  __shared__ int code2_l[64];
  __shared__ float rloss[64];
  int tid = threadIdx.x;
  int b  = blockIdx.x >> 5;
  int t0 = (blockIdx.x & 31) << 6;
  int tt = tid & 63, w = tid >> 6;

  if (w == 0) {
    unsigned long long key0 = keys[(size_t)b * T_ + t0 + tt];
    int idx0 = (int)(key0 & 0xFFFFFFFFULL);
    float s0 = unpack_dist(key0);
    unsigned long long k1 = keysM[idx0];
    int c1 = (int)(k1 & 0xFFFFFFFFULL);
    unsigned long long k2 = keysM[1024 + c1];
    code2_l[tt] = (int)(k2 & 0xFFFFFFFFULL);
    rloss[tt] = s0 + nrm[idx0] + unpack_dist(k1) + nrm[1024 + c1] + unpack_dist(k2);
  }
  __syncthreads();

  float* ob = out + ((size_t)b << 19);
  int code2 = code2_l[tt];
  const float* e2row = emb2 + (size_t)code2 * C_;
  for (int c4 = w * 64; c4 < w * 64 + 64; c4 += 4) {
    float4 ev = *(const float4*)(e2row + c4);
    float evv[4] = {ev.x, ev.y, ev.z, ev.w};
#pragma unroll
    for (int u = 0; u < 4; u++)
      ob[(size_t)(c4 + u) * T_ + t0 + tt] = evv[u];
  }
  if (w == 0) {
    float tot = rloss[tt];
    for (int off = 32; off > 0; off >>= 1)
      tot += __shfl_down(tot, off, 64);
    if (tt == 0) atomicAdd(loss_accum, tot);
  }
}

__global__ void finalize_kernel(const float* __restrict__ loss_accum,
                                float* __restrict__ out_loss) {
  *out_loss = 2.0f * (*loss_accum) / 8388608.0f;
}

extern "C" void kernel_launch(void* const* d_in, const int* in_sizes, int n_in,
                              void* d_out, int out_size, void* d_ws, size_t ws_size,
                              hipStream_t stream) {
  const float* x  = (const float*)d_in[0];
  const float* e0 = (const float*)d_in[1];
  const float* e1 = (const float*)d_in[2];
  const float* e2 = (const float*)d_in[3];
  float* out = (float*)d_out;
  char* ws = (char*)d_ws;

  unsigned long long* keys  = (unsigned long long*)ws;            // 262144 B
  unsigned long long* keysM = (unsigned long long*)(ws + 262144); // 16384 B
  float* nrm  = (float*)(ws + 278528);                            // 12288 B
  float* loss_accum = (float*)(ws + 290816);                      // 4 B
  unsigned short* embbf = (unsigned short*)(ws + 294912);         // 524288 B
  unsigned short* xT    = (unsigned short*)(ws + 819200);         // 16777216 B

  prep_kernel<<<272, 256, 0, stream>>>(e0, e1, e2, nrm, embbf, (uint4*)keysM, loss_accum);
  xpose_kernel<<<2048, 256, 0, stream>>>(x, xT, loss_accum);
  l0_mfma_kernel<<<256, 256, 98304, stream>>>(xT, embbf, nrm, keys);
  map_tile_kernel<<<512, 256, 0, stream>>>(e0, e1, e2, nrm, keysM);
  finish_kernel<<<512, 256, 0, stream>>>(e2, keys, keysM, nrm, out, loss_accum);
  finalize_kernel<<<1, 1, 0, stream>>>(loss_accum, out + TOTAL_ELEMS);
}

// Round 7
// 92.488 us; speedup vs baseline: 1.2473x; 1.1968x over previous
//
#include <hip/hip_runtime.h>
#include <stdint.h>

// Problem constants
#define B_  16
#define C_  256
#define T_  2048
#define K_  1024
#define TOTAL_ELEMS 8388608   // B*C*T

typedef short bf16x8 __attribute__((ext_vector_type(8)));
typedef float f32x4 __attribute__((ext_vector_type(4)));

// ---------- packed (dist, idx) ordering helpers ----------
__device__ __forceinline__ unsigned long long pack_key(float d, int idx) {
  unsigned u = __float_as_uint(d);
  u = (u & 0x80000000u) ? ~u : (u | 0x80000000u);   // monotone map f32 -> u32
  return ((unsigned long long)u << 32) | (unsigned)idx;
}
__device__ __forceinline__ float unpack_dist(unsigned long long key) {
  unsigned du = (unsigned)(key >> 32);
  unsigned bits = (du & 0x80000000u) ? (du ^ 0x80000000u) : ~du;
  return __uint_as_float(bits);
}

__device__ __forceinline__ unsigned short f2bf_rne(float f) {
  unsigned u = __float_as_uint(f);
  unsigned r = u + 0x7FFFu + ((u >> 16) & 1u);
  return (unsigned short)(r >> 16);
}

__device__ __forceinline__ void gload_lds16(const void* g, void* l) {
  __builtin_amdgcn_global_load_lds(
      (const __attribute__((address_space(1))) unsigned int*)g,
      (__attribute__((address_space(3))) unsigned int*)l, 16, 0, 0);
}

// ---------- prep: norms (0..11) + e0->bf16 (12..267) + keysM/loss/counter init (268..271) ----------
__global__ __launch_bounds__(256) void prep_kernel(
    const float* __restrict__ e0, const float* __restrict__ e1,
    const float* __restrict__ e2, float* __restrict__ nrm,
    unsigned short* __restrict__ ebf, uint4* __restrict__ keysM_region,
    float* __restrict__ loss_accum, unsigned* __restrict__ counter) {
  int bid = blockIdx.x;
  int tid = threadIdx.x;
  if (bid < 12) {
    int i = bid * 256 + tid;             // 0..3071
    const float* e = (i < 1024) ? e0 : (i < 2048) ? e1 : e2;
    const float* p = e + (size_t)(i & 1023) * C_;
    float s = 0.0f;
    for (int c = 0; c < C_; c += 4) {
      float4 v = *(const float4*)(p + c);
      s = fmaf(v.x, v.x, s); s = fmaf(v.y, v.y, s);
      s = fmaf(v.z, v.z, s); s = fmaf(v.w, v.w, s);
    }
    nrm[i] = s;
  } else if (bid < 268) {
    int i = (bid - 12) * 256 + tid;      // quad id, 0..65535
    float4 v = *(const float4*)(e0 + (size_t)i * 4);
    unsigned lo = (unsigned)f2bf_rne(v.x) | ((unsigned)f2bf_rne(v.y) << 16);
    unsigned hi = (unsigned)f2bf_rne(v.z) | ((unsigned)f2bf_rne(v.w) << 16);
    *(uint2*)(ebf + (size_t)i * 4) = make_uint2(lo, hi);
  } else {
    // init keysM (16384 B = 1024 uint4) + loss_accum + counter
    int i = (bid - 268) * 256 + tid;     // 0..1023
    keysM_region[i] = make_uint4(0xFFFFFFFFu, 0xFFFFFFFFu, 0xFFFFFFFFu, 0xFFFFFFFFu);
    if (bid == 268 && tid == 0) { *loss_accum = 0.0f; *counter = 0u; }
  }
}

// ---------- code-to-code maps as tiled f32 GEMM + argmin ----------
__global__ __launch_bounds__(256) void map_tile_kernel(
    const float* __restrict__ e0, const float* __restrict__ e1,
    const float* __restrict__ e2, const float* __restrict__ nrm,
    unsigned long long* __restrict__ keysM) {
  __shared__ float As[16][68];
  __shared__ float Bs[16][68];
  int bid = blockIdx.x;
  int m = bid >> 8;
  int tb = bid & 255;
  int ar0 = (tb >> 4) << 6;
  int br0 = (tb & 15) << 6;
  const float* Ap = m ? e1 : e0;
  const float* Bp = m ? e2 : e1;
  const float* nB = nrm + (m + 1) * 1024;

  int tid = threadIdx.x;
  int ty = tid >> 4, tx = tid & 15;
  int srow = tid >> 2;
  int skp  = (tid & 3) << 2;

  float acc[4][4];
#pragma unroll
  for (int i = 0; i < 4; i++)
#pragma unroll
    for (int j = 0; j < 4; j++) acc[i][j] = 0.0f;

  const float* gA = Ap + (size_t)(ar0 + srow) * C_ + skp;
  const float* gB = Bp + (size_t)(br0 + srow) * C_ + skp;

  for (int kk = 0; kk < C_; kk += 16) {
    float4 av = *(const float4*)(gA + kk);
    float4 bv = *(const float4*)(gB + kk);
    __syncthreads();
    As[skp + 0][srow] = av.x; As[skp + 1][srow] = av.y;
    As[skp + 2][srow] = av.z; As[skp + 3][srow] = av.w;
    Bs[skp + 0][srow] = bv.x; Bs[skp + 1][srow] = bv.y;
    Bs[skp + 2][srow] = bv.z; Bs[skp + 3][srow] = bv.w;
    __syncthreads();
#pragma unroll
    for (int k = 0; k < 16; k++) {
      float4 a4 = *(const float4*)&As[k][ty * 4];
      float4 b4 = *(const float4*)&Bs[k][tx * 4];
      float aa[4] = {a4.x, a4.y, a4.z, a4.w};
      float bb[4] = {b4.x, b4.y, b4.z, b4.w};
#pragma unroll
      for (int i = 0; i < 4; i++)
#pragma unroll
        for (int j = 0; j < 4; j++)
          acc[i][j] = fmaf(aa[i], bb[j], acc[i][j]);
    }
  }

  float nv[4];
#pragma unroll
  for (int j = 0; j < 4; j++) nv[j] = nB[br0 + tx * 4 + j];

#pragma unroll
  for (int i = 0; i < 4; i++) {
    unsigned long long best = 0xFFFFFFFFFFFFFFFFULL;
#pragma unroll
    for (int j = 0; j < 4; j++) {
      int code = br0 + tx * 4 + j;
      float s = nv[j] - 2.0f * acc[i][j];
      unsigned long long key = pack_key(s, code);
      if (key < best) best = key;
    }
#pragma unroll
    for (int off = 1; off < 16; off <<= 1) {
      unsigned long long o = __shfl_xor(best, off, 64);
      if (o < best) best = o;
    }
    if (tx == 0)
      atomicMin(&keysM[m * 1024 + ar0 + ty * 4 + i], best);
  }
}

// ---------- layer-0 fused: x transpose+cvt -> LDS A-tile, MFMA dist-GEMM, argmin, sum(x^2) ----------
// 256 blocks (1/CU), 512 threads (8 waves -> 2/SIMD). A[128 rows][256 c] bf16 = 64 KB,
// swizzled: chunk cc (8 c's) of row at byte row*512 + ((cc>>2 ^ ((row>>2)&1))<<6)
//           + (((cc&3) ^ (row&3))<<4). B: 4 chunks of 256 codes, dbuf 2x16 KB per kk-step,
// seg swizzle key (code ^ code>>2)&3 -> 2-way max. acc init = -||e||^2/2 so acc = -s/2;
// running (max,meta) in regs; keys written directly (no atomics, no init).
__global__ __launch_bounds__(512, 2) void l0_fused_kernel(
    const float* __restrict__ x, const unsigned short* __restrict__ ebf,
    const float* __restrict__ e0n, unsigned long long* __restrict__ keys,
    float* __restrict__ loss_accum) {
  extern __shared__ char smem[];            // 96 KB dynamic
  char* Abuf = smem;                        // 64 KB
  char* Bbuf = smem + 65536;                // 32 KB (2 x 16 KB dbuf)

  int tid = threadIdx.x;                    // 0..511
  int l = tid & 63, w = tid >> 6;
  int row0 = blockIdx.x << 7;

  // ---- phase 1: A-fill from x (transpose+cvt) + sum(x^2) ----
  {
    int row = tid & 127;                    // t within tile
    int cg  = tid >> 7;                     // 0..3
    int bb  = blockIdx.x >> 4;
    int t0  = (blockIdx.x & 15) << 7;
    const float* xb = x + (size_t)bb * (C_ * T_) + t0 + row;
    float sumsq = 0.0f;
#pragma unroll
    for (int i = 0; i < 8; i++) {
      int c0 = cg * 64 + i * 8;
      float v[8];
#pragma unroll
      for (int u = 0; u < 8; u++) {
        v[u] = xb[(size_t)(c0 + u) * T_];
        sumsq = fmaf(v[u], v[u], sumsq);
      }
      unsigned pk[4];
#pragma unroll
      for (int j = 0; j < 4; j++)
        pk[j] = (unsigned)f2bf_rne(v[2 * j]) | ((unsigned)f2bf_rne(v[2 * j + 1]) << 16);
      int cc = c0 >> 3;
      char* dst = Abuf + row * 512 + ((((cc >> 2)) ^ ((row >> 2) & 1)) << 6) +
                  (((cc & 3) ^ (row & 3)) << 4);
      *(uint4*)dst = make_uint4(pk[0], pk[1], pk[2], pk[3]);
    }
    for (int off = 32; off > 0; off >>= 1) sumsq += __shfl_down(sumsq, off, 64);
    float* red = (float*)(Bbuf + 16384);    // lives in d=1 buffer, consumed before staged
    if (l == 0) red[w] = sumsq;
    __syncthreads();
    if (tid == 0) {
      float s = 0.0f;
#pragma unroll
      for (int i = 0; i < 8; i++) s += red[i];
      atomicAdd(loss_accum, s);
    }
  }

  // ---- B staging: wave w covers codes [w*32, w*32+32) of chunk p, k-step kk ----
#define STAGEB(d_, p_, kk_) do {                                             \
    char* bbase = Bbuf + (d_) * 16384 + (w * 32) * 64;                       \
    _Pragma("unroll")                                                        \
    for (int j_ = 0; j_ < 2; j_++) {                                         \
      int code_ = (p_) * 256 + w * 32 + j_ * 16 + (l >> 2);                  \
      int seg_ = (l & 3) ^ ((l >> 2) & 3) ^ ((l >> 4) & 3);                  \
      gload_lds16(ebf + (((size_t)code_) << 8) + ((kk_) << 5) + (seg_ << 3), \
                  bbase + j_ * 1024);                                        \
    } } while (0)

  STAGEB(0, 0, 0);
  __syncthreads();

  int wr = w >> 2, wc = w & 3;
  int lr = l & 15, lg = l >> 4;
  int akb1 = (lr >> 2) & 1;
  int asegoff = (lg ^ (lr & 3)) << 4;
  int bsegoff = (lg ^ ((lr ^ (lr >> 2)) & 3)) << 4;

  f32x4 acc[4][4];
  float bestv[4][4];
  int   bestm[4][4];
#pragma unroll
  for (int mi = 0; mi < 4; mi++)
#pragma unroll
    for (int r = 0; r < 4; r++) { bestv[mi][r] = -1e30f; bestm[mi][r] = 0; }

  int d = 0;
  for (int p = 0; p < 4; p++) {
#pragma unroll
    for (int ni = 0; ni < 4; ni++) {
      float iv = -0.5f * e0n[p * 256 + wc * 64 + ni * 16 + lr];
      f32x4 ivv = {iv, iv, iv, iv};
#pragma unroll
      for (int mi = 0; mi < 4; mi++) acc[mi][ni] = ivv;
    }
#pragma unroll
    for (int kk = 0; kk < 8; kk++) {
      if (kk < 7) { STAGEB(d ^ 1, p, kk + 1); }
      else if (p < 3) { STAGEB(d ^ 1, p + 1, 0); }
      bf16x8 aF[4], bF[4];
#pragma unroll
      for (int mi = 0; mi < 4; mi++)
        aF[mi] = *(const bf16x8*)(Abuf + (wr * 64 + mi * 16 + lr) * 512 +
                                  ((kk ^ akb1) << 6) + asegoff);
#pragma unroll
      for (int ni = 0; ni < 4; ni++)
        bF[ni] = *(const bf16x8*)(Bbuf + d * 16384 +
                                  (wc * 64 + ni * 16 + lr) * 64 + bsegoff);
#pragma unroll
      for (int mi = 0; mi < 4; mi++)
#pragma unroll
        for (int ni = 0; ni < 4; ni++)
          acc[mi][ni] = __builtin_amdgcn_mfma_f32_16x16x32_bf16(
              aF[mi], bF[ni], acc[mi][ni], 0, 0, 0);
      __syncthreads();
      d ^= 1;
    }
    // fold chunk into running best (strict > keeps lowest code on ties)
#pragma unroll
    for (int mi = 0; mi < 4; mi++)
#pragma unroll
      for (int r = 0; r < 4; r++)
#pragma unroll
        for (int ni = 0; ni < 4; ni++) {
          float v = acc[mi][ni][r];
          if (v > bestv[mi][r]) { bestv[mi][r] = v; bestm[mi][r] = p * 4 + ni; }
        }
  }
#undef STAGEB

  // ---- epilogue: cross-lane reduce, direct keys write (Bbuf reused as kred) ----
  unsigned long long (*kred)[4] = (unsigned long long(*)[4])Bbuf;
#pragma unroll
  for (int mi = 0; mi < 4; mi++)
#pragma unroll
    for (int r = 0; r < 4; r++) {
      float sdist = -2.0f * bestv[mi][r];
      int m = bestm[mi][r];
      int code = ((m >> 2) << 8) | (wc << 6) | ((m & 3) << 4) | lr;
      unsigned long long key = pack_key(sdist, code);
#pragma unroll
      for (int off = 1; off < 16; off <<= 1) {
        unsigned long long o = __shfl_xor(key, off, 64);
        if (o < key) key = o;
      }
      if (lr == 0) kred[wr * 64 + mi * 16 + lg * 4 + r][wc] = key;
    }
  __syncthreads();
  if (tid < 128) {
    unsigned long long b0 = kred[tid][0], b1 = kred[tid][1];
    unsigned long long b2 = kred[tid][2], b3 = kred[tid][3];
    if (b1 < b0) b0 = b1;
    if (b3 < b2) b2 = b3;
    keys[row0 + tid] = b0 < b2 ? b0 : b2;
  }
}

// ---------- gather output + per-(b,t) loss terms + fused finalize ----------
__global__ __launch_bounds__(256) void finish_kernel(
    const float* __restrict__ emb2,
    const unsigned long long* __restrict__ keys,
    const unsigned long long* __restrict__ keysM,
    const float* __restrict__ nrm,
    float* __restrict__ out, float* __restrict__ loss_accum,
    unsigned* __restrict__ counter) {
  __shared__ int code2_l[64];
  __shared__ float rloss[64];
  int tid = threadIdx.x;
  int b  = blockIdx.x >> 5;
  int t0 = (blockIdx.x & 31) << 6;
  int tt = tid & 63, w = tid >> 6;

  if (w == 0) {
    unsigned long long key0 = keys[(size_t)b * T_ + t0 + tt];
    int idx0 = (int)(key0 & 0xFFFFFFFFULL);
    float s0 = unpack_dist(key0);
    unsigned long long k1 = keysM[idx0];
    int c1 = (int)(k1 & 0xFFFFFFFFULL);
    unsigned long long k2 = keysM[1024 + c1];
    code2_l[tt] = (int)(k2 & 0xFFFFFFFFULL);
    rloss[tt] = s0 + nrm[idx0] + unpack_dist(k1) + nrm[1024 + c1] + unpack_dist(k2);
  }
  __syncthreads();

  float* ob = out + ((size_t)b << 19);
  int code2 = code2_l[tt];
  const float* e2row = emb2 + (size_t)code2 * C_;
  for (int c4 = w * 64; c4 < w * 64 + 64; c4 += 4) {
    float4 ev = *(const float4*)(e2row + c4);
    float evv[4] = {ev.x, ev.y, ev.z, ev.w};
#pragma unroll
    for (int u = 0; u < 4; u++)
      ob[(size_t)(c4 + u) * T_ + t0 + tt] = evv[u];
  }
  if (w == 0) {
    float tot = rloss[tt];
    for (int off = 32; off > 0; off >>= 1)
      tot += __shfl_down(tot, off, 64);
    if (tt == 0) atomicAdd(loss_accum, tot);
  }
  if (tid == 0) {
    __threadfence();
    unsigned old = atomicAdd(counter, 1u);
    if (old == 511u) {
      float L = atomicAdd(loss_accum, 0.0f);   // device-scope read
      out[TOTAL_ELEMS] = 2.0f * L / 8388608.0f;
    }
  }
}

extern "C" void kernel_launch(void* const* d_in, const int* in_sizes, int n_in,
                              void* d_out, int out_size, void* d_ws, size_t ws_size,
                              hipStream_t stream) {
  const float* x  = (const float*)d_in[0];
  const float* e0 = (const float*)d_in[1];
  const float* e1 = (const float*)d_in[2];
  const float* e2 = (const float*)d_in[3];
  float* out = (float*)d_out;
  char* ws = (char*)d_ws;

  unsigned long long* keys  = (unsigned long long*)ws;            // 262144 B
  unsigned long long* keysM = (unsigned long long*)(ws + 262144); // 16384 B
  float* nrm  = (float*)(ws + 278528);                            // 12288 B
  float* loss_accum = (float*)(ws + 290816);                      // 4 B
  unsigned* counter = (unsigned*)(ws + 290820);                   // 4 B
  unsigned short* embbf = (unsigned short*)(ws + 294912);         // 524288 B

  prep_kernel<<<272, 256, 0, stream>>>(e0, e1, e2, nrm, embbf, (uint4*)keysM,
                                       loss_accum, counter);
  l0_fused_kernel<<<256, 512, 98304, stream>>>(x, embbf, nrm, keys, loss_accum);
  map_tile_kernel<<<512, 256, 0, stream>>>(e0, e1, e2, nrm, keysM);
  finish_kernel<<<512, 256, 0, stream>>>(e2, keys, keysM, nrm, out, loss_accum, counter);
}